// Round 1
// baseline (223.910 us; speedup 1.0000x reference)
//
#include <hip/hip_runtime.h>
#include <hip/hip_bf16.h>

// Problem constants (fixed by setup_inputs): N=2048, d=256, T=256, Q=64
#define NN   2048
#define DD   256
#define TT   256
#define NYC  16384           // T*Q flattened y columns
#define NCHUNK_XY 64         // 16384 / 256 cols per chunk
#define NCHUNK_XX 8          // 2048 / 256
#define CHUNK_COLS 256

static constexpr float INV_TEMP = 1.0f / 0.3f;

typedef __bf16 bf16x8 __attribute__((ext_vector_type(8)));
typedef __bf16 bf16x4 __attribute__((ext_vector_type(4)));
typedef float  f32x4  __attribute__((ext_vector_type(4)));

// ---------------------------------------------------------------- convert
__global__ void cvt_kernel(const float* __restrict__ in, __bf16* __restrict__ out, int n4) {
    int i = blockIdx.x * blockDim.x + threadIdx.x;
    const int stride = gridDim.x * blockDim.x;
    const float4* in4 = (const float4*)in;
    for (; i < n4; i += stride) {
        float4 v = in4[i];
        bf16x4 o;
        o[0] = (__bf16)v.x; o[1] = (__bf16)v.y; o[2] = (__bf16)v.z; o[3] = (__bf16)v.w;
        *(bf16x4*)(out + 4 * (size_t)i) = o;
    }
}

// ---------------------------------------------------------------- stats
// Grid: (16, 72). blockIdx.x = 128-row block. blockIdx.y: 0..63 -> XY chunk,
// 64..71 -> XX chunk. Block = 256 threads = 4 waves; wave w owns rows
// rowblk*128 + w*32 .. +31 (two 16-row MFMA row-tiles) and all 256 chunk cols.
__global__ void stats_kernel(const __bf16* __restrict__ xbf, const __bf16* __restrict__ ybf,
                             const int* __restrict__ tid,
                             float* __restrict__ xyT, float* __restrict__ xyP,
                             float* __restrict__ xxT, float* __restrict__ xxP,
                             float* __restrict__ diag) {
    const int w    = threadIdx.x >> 6;
    const int lane = threadIdx.x & 63;
    const int c16  = lane & 15;   // column-in-tile / frag row selector
    const int q    = lane >> 4;   // quad 0..3
    const int rowbase = blockIdx.x * 128 + w * 32;

    const int by    = blockIdx.y;
    const int mode  = (by < NCHUNK_XY) ? 0 : 1;           // 0 = x@y^T, 1 = x@x^T
    const int chunk = mode ? (by - NCHUNK_XY) : by;
    const int colbase = chunk * CHUNK_COLS;
    const __bf16* colmat = mode ? xbf : ybf;
    float* outT = mode ? (xxT + (size_t)chunk * NN) : (xyT + (size_t)chunk * NN);
    float* outP = mode ? (xxP + (size_t)chunk * NN) : (xyP + (size_t)chunk * NN);

    // Preload all A fragments for this wave's 32 rows (full K=256 in registers).
    // A[m][k]: m = lane&15, k = q*8 + j   (HW-verified layout)
    bf16x8 afrag[2][8];
#pragma unroll
    for (int t = 0; t < 2; t++) {
        const __bf16* base = xbf + (size_t)(rowbase + t * 16 + c16) * DD + q * 8;
#pragma unroll
        for (int ks = 0; ks < 8; ks++)
            afrag[t][ks] = *(const bf16x8*)(base + ks * 32);
    }
    // Track id of each of this lane's 8 C-rows (C row = q*4 + r per tile)
    int tidrow[2][4];
#pragma unroll
    for (int t = 0; t < 2; t++)
#pragma unroll
        for (int r = 0; r < 4; r++)
            tidrow[t][r] = tid[rowbase + t * 16 + q * 4 + r];

    float tot[2][4] = {}, pos[2][4] = {};

    for (int ct = 0; ct < CHUNK_COLS / 16; ct++) {
        const int col0 = colbase + ct * 16;
        const __bf16* bbase = colmat + (size_t)(col0 + c16) * DD + q * 8;
        f32x4 acc0 = {0.f, 0.f, 0.f, 0.f};
        f32x4 acc1 = {0.f, 0.f, 0.f, 0.f};
#pragma unroll
        for (int ks = 0; ks < 8; ks++) {
            bf16x8 b = *(const bf16x8*)(bbase + ks * 32);
            acc0 = __builtin_amdgcn_mfma_f32_16x16x32_bf16(afrag[0][ks], b, acc0, 0, 0, 0);
            acc1 = __builtin_amdgcn_mfma_f32_16x16x32_bf16(afrag[1][ks], b, acc1, 0, 0, 0);
        }
        const int colg = col0 + c16;
        const int coltid = mode ? tid[colg] : (colg & (TT - 1));
#pragma unroll
        for (int t = 0; t < 2; t++) {
            f32x4 acc = t ? acc1 : acc0;
#pragma unroll
            for (int r = 0; r < 4; r++) {
                float val = __expf(acc[r] * INV_TEMP);
                tot[t][r] += val;
                pos[t][r] += (coltid == tidrow[t][r]) ? val : 0.f;
                if (mode && colg == rowbase + t * 16 + q * 4 + r)
                    diag[colg] = val;   // unique writer per diagonal element
            }
        }
    }

    // Reduce each row's sums across the 16 lanes that share (q, r)
#pragma unroll
    for (int t = 0; t < 2; t++)
#pragma unroll
        for (int r = 0; r < 4; r++) {
            float a = tot[t][r], p = pos[t][r];
#pragma unroll
            for (int off = 1; off < 16; off <<= 1) {
                a += __shfl_xor(a, off);
                p += __shfl_xor(p, off);
            }
            if (c16 == 0) {
                int row = rowbase + t * 16 + q * 4 + r;
                outT[row] = a;
                outP[row] = p;
            }
        }
}

// ---------------------------------------------------------------- finalize
__global__ void finalize_kernel(const float* __restrict__ xyT, const float* __restrict__ xyP,
                                const float* __restrict__ xxT, const float* __restrict__ xxP,
                                const float* __restrict__ diag, const int* __restrict__ tid,
                                float* __restrict__ out) {
    __shared__ float num_s[TT], den_s[TT];
    __shared__ int cnt_s[TT];
    const int t = threadIdx.x;  // 256 threads
    num_s[t] = 0.f; den_s[t] = 0.f; cnt_s[t] = 0;
    __syncthreads();
    for (int i = t; i < NN; i += 256) {
        float rxyt = 0.f, rxyp = 0.f, rxxt = 0.f, rxxp = 0.f;
#pragma unroll 8
        for (int c = 0; c < NCHUNK_XY; c++) { rxyt += xyT[c * NN + i]; rxyp += xyP[c * NN + i]; }
#pragma unroll
        for (int c = 0; c < NCHUNK_XX; c++) { rxxt += xxT[c * NN + i]; rxxp += xxP[c * NN + i]; }
        float num_i = rxyp + 0.5f * (rxxp - diag[i]);
        float den_i = (rxyt - rxyp) + (rxxt - rxxp);
        int tr = tid[i];
        atomicAdd(&num_s[tr], num_i);
        atomicAdd(&den_s[tr], den_i);
        atomicAdd(&cnt_s[tr], 1);
    }
    __syncthreads();
    float lt = 0.f, pr = 0.f;
    if (cnt_s[t] > 0) {
        lt = -logf(num_s[t] / (den_s[t] + num_s[t]));
        pr = 1.f;
    }
    for (int off = 32; off; off >>= 1) { lt += __shfl_down(lt, off); pr += __shfl_down(pr, off); }
    __shared__ float ls[4], ps[4];
    if ((t & 63) == 0) { ls[t >> 6] = lt; ps[t >> 6] = pr; }
    __syncthreads();
    if (t == 0) out[0] = (ls[0] + ls[1] + ls[2] + ls[3]) / (ps[0] + ps[1] + ps[2] + ps[3]);
}

// ---------------------------------------------------------------- launch
extern "C" void kernel_launch(void* const* d_in, const int* in_sizes, int n_in,
                              void* d_out, int out_size, void* d_ws, size_t ws_size,
                              hipStream_t stream) {
    const float* x   = (const float*)d_in[0];
    const int*   tid = (const int*)d_in[1];
    const float* y   = (const float*)d_in[2];
    float* out = (float*)d_out;

    char* ws = (char*)d_ws;
    __bf16* xbf = (__bf16*)ws;                                   // 2048*256*2 = 1 MB
    __bf16* ybf = (__bf16*)(ws + (1u << 20));                    // 16384*256*2 = 8 MB
    float* xyT  = (float*)(ws + 9u * (1u << 20));                // 64*2048 f32
    float* xyP  = xyT + (size_t)NCHUNK_XY * NN;
    float* xxT  = xyP + (size_t)NCHUNK_XY * NN;
    float* xxP  = xxT + (size_t)NCHUNK_XX * NN;
    float* diag = xxP + (size_t)NCHUNK_XX * NN;                  // total ~10.2 MB

    cvt_kernel<<<512, 256, 0, stream>>>(x, xbf, NN * DD / 4);
    cvt_kernel<<<2048, 256, 0, stream>>>(y, ybf, NYC * DD / 4);
    stats_kernel<<<dim3(16, NCHUNK_XY + NCHUNK_XX), 256, 0, stream>>>(
        xbf, ybf, tid, xyT, xyP, xxT, xxP, diag);
    finalize_kernel<<<1, 256, 0, stream>>>(xyT, xyP, xxT, xxP, diag, tid, out);
}

// Round 2
// 114.425 us; speedup vs baseline: 1.9568x; 1.9568x over previous
//
#include <hip/hip_runtime.h>
#include <hip/hip_bf16.h>

// Problem constants (fixed by setup_inputs): N=2048, d=256, T=256, Q=64
#define NN   2048
#define DD   256
#define TT   256
#define NYC  16384           // T*Q flattened y columns
#define NCHUNK_XY 64         // 16384 / 256 cols per chunk
#define NCHUNK_XX 8          // 2048 / 256
#define CHUNK_COLS 256
#define PAIR_BYTES 1040      // 2 cols (1024 B) + 16 B pad -> breaks bank aliasing
#define TILE_BYTES (8 * PAIR_BYTES)

static constexpr float INV_TEMP = 1.0f / 0.3f;

typedef __bf16 bf16x8 __attribute__((ext_vector_type(8)));
typedef __bf16 bf16x4 __attribute__((ext_vector_type(4)));
typedef float  f32x4  __attribute__((ext_vector_type(4)));

// ------------------------------------------------ convert + zero accumulators
__global__ void cvt_zero_kernel(const float* __restrict__ x, const float* __restrict__ y,
                                __bf16* __restrict__ xbf, __bf16* __restrict__ ybf,
                                float* __restrict__ acc /* 3*NN floats: Tot,Pxy,Pxx */) {
    const int tid0   = blockIdx.x * blockDim.x + threadIdx.x;
    const int stride = gridDim.x * blockDim.x;
    for (int j = tid0; j < 3 * NN; j += stride) acc[j] = 0.f;
    const int nx4 = NN * DD / 4;
    const float4* x4 = (const float4*)x;
    for (int j = tid0; j < nx4; j += stride) {
        float4 v = x4[j];
        bf16x4 o; o[0] = (__bf16)v.x; o[1] = (__bf16)v.y; o[2] = (__bf16)v.z; o[3] = (__bf16)v.w;
        *(bf16x4*)(xbf + 4 * (size_t)j) = o;
    }
    const int ny4 = NYC * DD / 4;
    const float4* y4 = (const float4*)y;
    for (int j = tid0; j < ny4; j += stride) {
        float4 v = y4[j];
        bf16x4 o; o[0] = (__bf16)v.x; o[1] = (__bf16)v.y; o[2] = (__bf16)v.z; o[3] = (__bf16)v.w;
        *(bf16x4*)(ybf + 4 * (size_t)j) = o;
    }
}

// ------------------------------------------------ stats (GEMM + exp + grouped sums)
// Grid (16, 72): x = 128-row block, y = 0..63 XY chunk / 64..71 XX chunk.
// 256 threads = 4 waves; wave w owns rows rowblk*128 + w*32 .. +31.
// Per 16-col tile: stage 8 KB of B into LDS (coalesced, double-buffered),
// all waves read fragments from LDS.
__global__ void stats_kernel(const __bf16* __restrict__ xbf, const __bf16* __restrict__ ybf,
                             const int* __restrict__ tid,
                             float* __restrict__ Tot, float* __restrict__ Pxy,
                             float* __restrict__ Pxx, float* __restrict__ diag) {
    __shared__ __align__(16) char bstage[2][TILE_BYTES];
    __shared__ int coltid_s[CHUNK_COLS];

    const int tix  = threadIdx.x;
    const int w    = tix >> 6;
    const int lane = tix & 63;
    const int c16  = lane & 15;
    const int q    = lane >> 4;
    const int rowbase = blockIdx.x * 128 + w * 32;

    const int by    = blockIdx.y;
    const int mode  = (by >= NCHUNK_XY);          // 0 = x@y^T, 1 = x@x^T
    const int chunk = mode ? (by - NCHUNK_XY) : by;
    const int colbase = chunk * CHUNK_COLS;
    const __bf16* colmat = mode ? xbf : ybf;

    coltid_s[tix] = mode ? tid[colbase + tix] : ((colbase + tix) & (TT - 1));

    // A fragments: full K=256 for this wave's 32 rows.
    bf16x8 afrag[2][8];
#pragma unroll
    for (int t = 0; t < 2; t++) {
        const __bf16* base = xbf + (size_t)(rowbase + t * 16 + c16) * DD + q * 8;
#pragma unroll
        for (int ks = 0; ks < 8; ks++)
            afrag[t][ks] = *(const bf16x8*)(base + ks * 32);
    }
    int tidrow[2][4];
#pragma unroll
    for (int t = 0; t < 2; t++)
#pragma unroll
        for (int r = 0; r < 4; r++)
            tidrow[t][r] = tid[rowbase + t * 16 + q * 4 + r];

    // Staging addresses: thread j copies bytes [j*32, j*32+32) of the 8 KB tile.
    const int pair = tix >> 5;                    // 0..7 (2-col pair)
    const int poff = (tix * 32) & 1023;           // offset within pair
    char* dst0 = &bstage[0][pair * PAIR_BYTES + poff];
    char* dst1 = &bstage[1][pair * PAIR_BYTES + poff];

    float4 pf0, pf1;
    {   // prefetch tile 0
        const __bf16* src = colmat + (size_t)colbase * DD + tix * 16;
        pf0 = *(const float4*)src;
        pf1 = *(const float4*)(src + 8);
    }

    float tot[2][4] = {}, pos[2][4] = {};

    for (int ct = 0; ct < CHUNK_COLS / 16; ct++) {
        char* dst = (ct & 1) ? dst1 : dst0;
        *(float4*)dst        = pf0;
        *(float4*)(dst + 16) = pf1;
        if (ct < 15) {
            const __bf16* src = colmat + (size_t)(colbase + (ct + 1) * 16) * DD + tix * 16;
            pf0 = *(const float4*)src;
            pf1 = *(const float4*)(src + 8);
        }
        __syncthreads();

        const char* bb = &bstage[ct & 1][(c16 >> 1) * PAIR_BYTES + (c16 & 1) * 512 + q * 16];
        f32x4 acc0 = {0.f, 0.f, 0.f, 0.f};
        f32x4 acc1 = {0.f, 0.f, 0.f, 0.f};
#pragma unroll
        for (int ks = 0; ks < 8; ks++) {
            bf16x8 b = *(const bf16x8*)(bb + ks * 64);
            acc0 = __builtin_amdgcn_mfma_f32_16x16x32_bf16(afrag[0][ks], b, acc0, 0, 0, 0);
            acc1 = __builtin_amdgcn_mfma_f32_16x16x32_bf16(afrag[1][ks], b, acc1, 0, 0, 0);
        }

        const int colg   = colbase + ct * 16 + c16;
        const int coltid = coltid_s[ct * 16 + c16];
#pragma unroll
        for (int t = 0; t < 2; t++) {
            f32x4 acc = t ? acc1 : acc0;
#pragma unroll
            for (int r = 0; r < 4; r++) {
                float val = __expf(acc[r] * INV_TEMP);
                tot[t][r] += val;
                pos[t][r] += (coltid == tidrow[t][r]) ? val : 0.f;
                if (mode && colg == rowbase + t * 16 + q * 4 + r)
                    diag[colg] = val;             // unique writer per diagonal elem
            }
        }
    }

    // Reduce across the 16 column-lanes sharing (q, r); then one atomic per row.
#pragma unroll
    for (int t = 0; t < 2; t++)
#pragma unroll
        for (int r = 0; r < 4; r++) {
            float a = tot[t][r], p = pos[t][r];
#pragma unroll
            for (int off = 1; off < 16; off <<= 1) {
                a += __shfl_xor(a, off);
                p += __shfl_xor(p, off);
            }
            if (c16 == 0) {
                const int row = rowbase + t * 16 + q * 4 + r;
                atomicAdd(&Tot[row], a);
                atomicAdd(mode ? &Pxx[row] : &Pxy[row], p);
            }
        }
}

// ------------------------------------------------ finalize (reads 32 KB only)
__global__ void finalize_kernel(const float* __restrict__ Tot, const float* __restrict__ Pxy,
                                const float* __restrict__ Pxx, const float* __restrict__ diag,
                                const int* __restrict__ tid, float* __restrict__ out) {
    __shared__ float num_s[TT], den_s[TT];
    __shared__ int cnt_s[TT];
    const int t = threadIdx.x;  // 256 threads
    num_s[t] = 0.f; den_s[t] = 0.f; cnt_s[t] = 0;
    __syncthreads();
    for (int i = t; i < NN; i += 256) {
        float tt_ = Tot[i], pxy = Pxy[i], pxx = Pxx[i];
        float num = pxy + 0.5f * (pxx - diag[i]);
        float den = tt_ - pxy - pxx;
        int tr = tid[i];
        atomicAdd(&num_s[tr], num);
        atomicAdd(&den_s[tr], den);
        atomicAdd(&cnt_s[tr], 1);
    }
    __syncthreads();
    float lt = 0.f, pr = 0.f;
    if (cnt_s[t] > 0) {
        lt = -logf(num_s[t] / (den_s[t] + num_s[t]));
        pr = 1.f;
    }
    for (int off = 32; off; off >>= 1) { lt += __shfl_down(lt, off); pr += __shfl_down(pr, off); }
    __shared__ float ls[4], ps[4];
    if ((t & 63) == 0) { ls[t >> 6] = lt; ps[t >> 6] = pr; }
    __syncthreads();
    if (t == 0) out[0] = (ls[0] + ls[1] + ls[2] + ls[3]) / (ps[0] + ps[1] + ps[2] + ps[3]);
}

// ------------------------------------------------ launch
extern "C" void kernel_launch(void* const* d_in, const int* in_sizes, int n_in,
                              void* d_out, int out_size, void* d_ws, size_t ws_size,
                              hipStream_t stream) {
    const float* x   = (const float*)d_in[0];
    const int*   tid = (const int*)d_in[1];
    const float* y   = (const float*)d_in[2];
    float* out = (float*)d_out;

    char* ws = (char*)d_ws;
    __bf16* xbf = (__bf16*)ws;                       // 1 MB
    __bf16* ybf = (__bf16*)(ws + (1u << 20));        // 8 MB
    float* acc  = (float*)(ws + 9u * (1u << 20));    // Tot,Pxy,Pxx: 3*2048 f32
    float* Tot  = acc;
    float* Pxy  = acc + NN;
    float* Pxx  = acc + 2 * NN;
    float* diag = acc + 3 * NN;                      // 2048 f32 (fully rewritten by stats)

    cvt_zero_kernel<<<1024, 256, 0, stream>>>(x, y, xbf, ybf, acc);
    stats_kernel<<<dim3(16, NCHUNK_XY + NCHUNK_XX), 256, 0, stream>>>(
        xbf, ybf, tid, Tot, Pxy, Pxx, diag);
    finalize_kernel<<<1, 256, 0, stream>>>(Tot, Pxy, Pxx, diag, tid, out);
}